// Round 1
// baseline (742.866 us; speedup 1.0000x reference)
//
#include <hip/hip_runtime.h>
#include <cstddef>

typedef short bf16x8 __attribute__((ext_vector_type(8)));
typedef float f32x4 __attribute__((ext_vector_type(4)));

__device__ __forceinline__ float sigm(float x) { return 1.f / (1.f + expf(-x)); }

// f32 -> bf16 (round to nearest even)
__device__ __forceinline__ unsigned short f2bf(float f) {
    union { float f; unsigned u; } v; v.f = f;
    return (unsigned short)((v.u + 0x7FFFu + ((v.u >> 16) & 1u)) >> 16);
}

// ============================================================================
// prep_cast: one pass producing all bf16 operands.
//  region0: Abf[20160][320bf16]  = emb rows gathered by input_ids(19200)+titles(960)
//  region1: Wsen[2048][320bf16]  = [sen_wih_f | sen_wih_b] (K 300 -> 320 zero-pad)
//  region2: Wdoc[2048][512bf16]  = [doc_wih_f | doc_wih_b]
// ============================================================================
#define N0 (20160 * 160)
#define N1 (2048 * 160)
#define N2 (2048 * 256)

__global__ __launch_bounds__(256) void prep_cast(
    const int* __restrict__ ids, const int* __restrict__ titles,
    const float* __restrict__ emb,
    const float* __restrict__ swf, const float* __restrict__ swb,
    const float* __restrict__ dwf, const float* __restrict__ dwb,
    unsigned* __restrict__ Abf, unsigned* __restrict__ Wsen,
    unsigned* __restrict__ Wdoc)
{
    int idx = blockIdx.x * 256 + threadIdx.x;
    if (idx < N0) {
        int row = idx / 160, kk = idx - row * 160;
        int id = (row < 19200) ? ids[row] : titles[row - 19200];
        float a = 0.f, b = 0.f;
        if (kk < 150) {
            const float* s = emb + (size_t)id * 300 + kk * 2;
            a = s[0]; b = s[1];
        }
        Abf[idx] = (unsigned)f2bf(a) | ((unsigned)f2bf(b) << 16);
    } else if (idx < N0 + N1) {
        int j = idx - N0;
        int row = j / 160, kk = j - row * 160;
        const float* base = (row < 1024) ? swf + (size_t)row * 300
                                         : swb + (size_t)(row - 1024) * 300;
        float a = 0.f, b = 0.f;
        if (kk < 150) { a = base[kk * 2]; b = base[kk * 2 + 1]; }
        Wsen[j] = (unsigned)f2bf(a) | ((unsigned)f2bf(b) << 16);
    } else if (idx < N0 + N1 + N2) {
        int j = idx - N0 - N1;
        int row = j >> 8, kk = j & 255;
        const float* base = (row < 1024) ? dwf + (size_t)row * 512
                                         : dwb + (size_t)(row - 1024) * 512;
        Wdoc[j] = (unsigned)f2bf(base[kk * 2]) | ((unsigned)f2bf(base[kk * 2 + 1]) << 16);
    }
}

// ============================================================================
// proj_mfma: out[M][2048] = Abf[M][Kp] @ Wbf^T + bias, output GATE-INTERLEAVED:
//   col = half*1024 + unit*4 + gate   (unit 0..255, gate 0..3 = i,f,g,o)
// ============================================================================
__global__ __launch_bounds__(256) void proj_mfma(
    const unsigned short* __restrict__ Abf, int M, int Kp,
    const unsigned short* __restrict__ Wbf,
    const float* __restrict__ bf_, const float* __restrict__ bb_,
    float* __restrict__ out)
{
    __shared__ unsigned short As[128 * 40];   // pitch 80B (16B aligned)
    __shared__ unsigned short Ws[128 * 40];
    const int tid  = threadIdx.x;
    const int lane = tid & 63;
    const int w    = tid >> 6;
    const int n    = lane & 15;
    const int quad = lane >> 4;
    const int bm   = blockIdx.x * 128;
    const int by   = blockIdx.y;              // 0..15
    const int half = by >> 3;
    const int ug32 = (by & 7) * 32;
    const unsigned short* Wb = Wbf + (size_t)half * 1024 * Kp;
    const float* biasp = half ? bb_ : bf_;

    f32x4 acc[2][8];
#pragma unroll
    for (int rt = 0; rt < 2; rt++)
#pragma unroll
        for (int ct = 0; ct < 8; ct++) acc[rt][ct] = (f32x4){0.f, 0.f, 0.f, 0.f};

    const int chunks = Kp >> 5;
    for (int kc = 0; kc < chunks; kc++) {
        const int k0 = kc * 32;
#pragma unroll
        for (int j = 0; j < 2; j++) {
            int idx = j * 256 + tid;
            int arow = idx >> 2, qq = idx & 3;
            int grow = bm + arow; if (grow >= M) grow = M - 1;
            *(uint4*)&As[arow * 40 + qq * 8] =
                *(const uint4*)(Abf + (size_t)grow * Kp + k0 + qq * 8);
            int cc = idx >> 2;
            int wrow = (cc >> 5) * 256 + ug32 + (cc & 31);   // gate=cc>>5, unit
            *(uint4*)&Ws[cc * 40 + qq * 8] =
                *(const uint4*)(Wb + (size_t)wrow * Kp + k0 + qq * 8);
        }
        __syncthreads();
        bf16x8 Aq[2], Bq[8];
#pragma unroll
        for (int rt = 0; rt < 2; rt++)
            Aq[rt] = *(const bf16x8*)&As[((w * 2 + rt) * 16 + n) * 40 + quad * 8];
#pragma unroll
        for (int ct = 0; ct < 8; ct++)
            Bq[ct] = *(const bf16x8*)&Ws[(ct * 16 + n) * 40 + quad * 8];
#pragma unroll
        for (int rt = 0; rt < 2; rt++)
#pragma unroll
            for (int ct = 0; ct < 8; ct++)
                acc[rt][ct] = __builtin_amdgcn_mfma_f32_16x16x32_bf16(
                    Aq[rt], Bq[ct], acc[rt][ct], 0, 0, 0);
        __syncthreads();
    }

#pragma unroll
    for (int s = 0; s < 2; s++) {
        const int uL = s * 16 + n;
        float b0 = biasp[ug32 + uL];
        float b1 = biasp[256 + ug32 + uL];
        float b2 = biasp[512 + ug32 + uL];
        float b3 = biasp[768 + ug32 + uL];
#pragma unroll
        for (int rt = 0; rt < 2; rt++) {
#pragma unroll
            for (int r = 0; r < 4; r++) {
                int row = bm + (w * 2 + rt) * 16 + quad * 4 + r;
                if (row >= M) continue;
                float4 o;
                o.x = acc[rt][0 + s][r] + b0;
                o.y = acc[rt][2 + s][r] + b1;
                o.z = acc[rt][4 + s][r] + b2;
                o.w = acc[rt][6 + s][r] + b3;
                *(float4*)(out + (size_t)row * 2048 + half * 1024 + (ug32 + uL) * 4) = o;
            }
        }
    }
}

// ---------------------------------------------------------------------------
// group barrier: 16 blocks, MONOTONIC counter, ALL RELAXED agent atomics.
// No acquire/release: every cross-block datum (h, counter) travels via
// coherence-point-bypassing atomics, so no cache maintenance is needed.
// __syncthreads drains each thread's h-stores (vmcnt) before arrival.
// ---------------------------------------------------------------------------
__device__ __forceinline__ void group_barrier(unsigned* cnt, unsigned target) {
    __syncthreads();
    if (threadIdx.x == 0) {
        __hip_atomic_fetch_add(cnt, 1u, __ATOMIC_RELAXED, __HIP_MEMORY_SCOPE_AGENT);
        while (__hip_atomic_load(cnt, __ATOMIC_RELAXED, __HIP_MEMORY_SCOPE_AGENT) < target)
            __builtin_amdgcn_s_sleep(1);
    }
    __syncthreads();
}

__device__ __forceinline__ const float* sen_xbase(
    const float* xw, const float* xw_head, int grow_e, int t)
{
    if (grow_e < 640)       return xw + ((size_t)grow_e * 30 + t) * 2048;
    else if (grow_e < 1280) return xw + ((size_t)(grow_e - 640) * 30 + 29 - t) * 2048 + 1024;
    else if (grow_e < 1344) return xw_head + ((size_t)(grow_e - 1280) * 15 + t) * 2048;
    else                    return xw_head + ((size_t)(grow_e - 1344) * 15 + 14 - t) * 2048 + 1024;
}

// ============================================================================
// lstm_sen: persistent BiLSTM, grid (16 unit-groups, 22 row-groups).
// Rows: 0..639 sen-fwd | 640..1279 sen-bwd | 1280..1343 head-f | 1344..1407 head-b.
// xw prefetched one step ahead (issued before the barrier wait).
// ============================================================================
__global__ __launch_bounds__(256, 2) void lstm_sen(
    const float* __restrict__ xw, const float* __restrict__ xw_head,
    const float* __restrict__ whh_f, const float* __restrict__ whh_b,
    unsigned short* hbA, unsigned short* hbB,
    float* __restrict__ sentences, float* __restrict__ headings,
    unsigned* bars)
{
    const int tid  = threadIdx.x;
    const int lane = tid & 63;
    const int w    = tid >> 6;
    const int n    = lane & 15;
    const int quad = lane >> 4;
    const int ug   = blockIdx.x;       // 0..15
    const int rg   = blockIdx.y;       // 0..21
    const int r0   = rg * 64;
    const int u0   = ug * 16;
    const bool bwd  = (rg >= 10 && rg < 20) || (rg == 21);
    const bool head = (rg >= 20);
    const float* whh = bwd ? whh_b : whh_f;
    unsigned* cnt = bars + rg * 16;    // 64B-separated counters
    const int tEnd = head ? 15 : 30;

    __shared__ float G[64][68];        // row pitch 272B (16B aligned)

    // Whh -> register B-frags. MFMA col cc=ct*16+n -> (unit uL=cc>>2, gate=cc&3);
    // W row = gate*256 + u0 + uL.
    bf16x8 Bf[4][8];
#pragma unroll
    for (int ct = 0; ct < 4; ct++) {
        const int c    = ct * 16 + n;
        const int grow = (c & 3) * 256 + u0 + (c >> 2);
        const float* wr = whh + (size_t)grow * 256;
#pragma unroll
        for (int ks = 0; ks < 8; ks++) {
            union { bf16x8 v; short s[8]; } tmp;
            const float* p = wr + ks * 32 + quad * 8;
#pragma unroll
            for (int j = 0; j < 8; j++) tmp.s[j] = (short)f2bf(p[j]);
            Bf[ct][ks] = tmp.v;
        }
    }

    float cr[4] = {0.f, 0.f, 0.f, 0.f};
    const int rr = tid >> 2;
    const int us = (tid & 3) * 4;             // local unit base
    const int grow_e = r0 + rr;

    // preload xw slice for t=0
    float4 xv[4];
    {
        const float4* xp = (const float4*)(sen_xbase(xw, xw_head, grow_e, 0)
                                           + (size_t)(u0 + us) * 4);
        xv[0] = xp[0]; xv[1] = xp[1]; xv[2] = xp[2]; xv[3] = xp[3];
    }

    for (int t = 0; t < tEnd; t++) {
        const unsigned short* hp = (t & 1) ? hbB : hbA;
        unsigned short*       hq = (t & 1) ? hbA : hbB;

        // ---- hidden GEMM (MFMA) ----
        {
            const unsigned long long* hrow =
                (const unsigned long long*)(hp + (size_t)(r0 + w * 16 + n) * 256);
            unsigned long long a0[8], a1[8];
#pragma unroll
            for (int ks = 0; ks < 8; ks++) {
                a0[ks] = __hip_atomic_load(hrow + ks * 8 + quad * 2,
                                           __ATOMIC_RELAXED, __HIP_MEMORY_SCOPE_AGENT);
                a1[ks] = __hip_atomic_load(hrow + ks * 8 + quad * 2 + 1,
                                           __ATOMIC_RELAXED, __HIP_MEMORY_SCOPE_AGENT);
            }
            f32x4 acc[4];
#pragma unroll
            for (int ct = 0; ct < 4; ct++) acc[ct] = (f32x4){0.f, 0.f, 0.f, 0.f};
#pragma unroll
            for (int ks = 0; ks < 8; ks++) {
                union { bf16x8 v; unsigned long long q[2]; } af;
                af.q[0] = a0[ks]; af.q[1] = a1[ks];
#pragma unroll
                for (int ct = 0; ct < 4; ct++)
                    acc[ct] = __builtin_amdgcn_mfma_f32_16x16x32_bf16(
                        af.v, Bf[ct][ks], acc[ct], 0, 0, 0);
            }
#pragma unroll
            for (int ct = 0; ct < 4; ct++)
#pragma unroll
                for (int r = 0; r < 4; r++)
                    G[w * 16 + quad * 4 + r][ct * 16 + n] = acc[ct][r];
        }
        __syncthreads();

        // ---- gate epilogue ----
        {
            float* fdst = nullptr;
            if (!head) {
                if (t == 29) fdst = sentences +
                    (size_t)(bwd ? grow_e - 640 : grow_e) * 512 + (bwd ? 256 : 0);
            } else {
                if (t == 14) fdst = headings +
                    (size_t)(grow_e - (bwd ? 1344 : 1280)) * 512 + (bwd ? 256 : 0);
            }
            const float4* Gp = (const float4*)&G[rr][us * 4];
            unsigned long long hpack = 0ull;
            float hout[4];
#pragma unroll
            for (int p = 0; p < 4; p++) {
                float4 gv = Gp[p];
                float4 xq = xv[p];
                float gi = gv.x + xq.x;
                float gf = gv.y + xq.y;
                float gg = gv.z + xq.z;
                float go = gv.w + xq.w;
                float cn = sigm(gf) * cr[p] + sigm(gi) * tanhf(gg);
                float hn = sigm(go) * tanhf(cn);
                cr[p] = cn; hout[p] = hn;
                hpack |= ((unsigned long long)f2bf(hn)) << (16 * p);
            }
            __hip_atomic_store((unsigned long long*)(hq + (size_t)grow_e * 256 + u0 + us),
                               hpack, __ATOMIC_RELAXED, __HIP_MEMORY_SCOPE_AGENT);
            if (fdst) *(float4*)(fdst + u0 + us) = *(float4*)hout;
        }

        if (t + 1 < tEnd) {
            // prefetch next step's xw BEFORE the barrier wait (h-independent)
            const float4* xp = (const float4*)(sen_xbase(xw, xw_head, grow_e, t + 1)
                                               + (size_t)(u0 + us) * 4);
            xv[0] = xp[0]; xv[1] = xp[1]; xv[2] = xp[2]; xv[3] = xp[3];
            group_barrier(cnt, 16u * (unsigned)(t + 1));
        }
    }
}

// ============================================================================
// lstm_doc: persistent BiLSTM over 64 docs x 10 steps. Grid (16, 2).
// ============================================================================
__global__ __launch_bounds__(256, 2) void lstm_doc(
    const float* __restrict__ xw,
    const float* __restrict__ whh_f, const float* __restrict__ whh_b,
    unsigned short* hbA, unsigned short* hbB,
    float* __restrict__ documents,
    unsigned* bars)
{
    const int tid  = threadIdx.x;
    const int lane = tid & 63;
    const int w    = tid >> 6;
    const int n    = lane & 15;
    const int quad = lane >> 4;
    const int ug   = blockIdx.x;       // 0..15
    const int rg   = blockIdx.y;       // 0..1
    const int r0   = rg * 64;
    const int u0   = ug * 16;
    const bool bwd = (rg == 1);
    const float* whh = bwd ? whh_b : whh_f;
    unsigned* cnt = bars + rg * 16;

    __shared__ float G[64][68];

    bf16x8 Bf[4][8];
#pragma unroll
    for (int ct = 0; ct < 4; ct++) {
        const int c    = ct * 16 + n;
        const int grow = (c & 3) * 256 + u0 + (c >> 2);
        const float* wr = whh + (size_t)grow * 256;
#pragma unroll
        for (int ks = 0; ks < 8; ks++) {
            union { bf16x8 v; short s[8]; } tmp;
            const float* p = wr + ks * 32 + quad * 8;
#pragma unroll
            for (int j = 0; j < 8; j++) tmp.s[j] = (short)f2bf(p[j]);
            Bf[ct][ks] = tmp.v;
        }
    }

    float cr[4] = {0.f, 0.f, 0.f, 0.f};
    const int rr = tid >> 2;
    const int us = (tid & 3) * 4;
    const int grow_e = r0 + rr;
    const int seq = rr;                        // doc index

    float4 xv[4];
    {
        const float* xb = !bwd ? xw + ((size_t)seq * 10 + 0) * 2048
                               : xw + ((size_t)seq * 10 + 9) * 2048 + 1024;
        const float4* xp = (const float4*)(xb + (size_t)(u0 + us) * 4);
        xv[0] = xp[0]; xv[1] = xp[1]; xv[2] = xp[2]; xv[3] = xp[3];
    }

    for (int t = 0; t < 10; t++) {
        const unsigned short* hp = (t & 1) ? hbB : hbA;
        unsigned short*       hq = (t & 1) ? hbA : hbB;
        const int dpos = !bwd ? t : 9 - t;
        const int doff = !bwd ? 0 : 256;

        {
            const unsigned long long* hrow =
                (const unsigned long long*)(hp + (size_t)(r0 + w * 16 + n) * 256);
            unsigned long long a0[8], a1[8];
#pragma unroll
            for (int ks = 0; ks < 8; ks++) {
                a0[ks] = __hip_atomic_load(hrow + ks * 8 + quad * 2,
                                           __ATOMIC_RELAXED, __HIP_MEMORY_SCOPE_AGENT);
                a1[ks] = __hip_atomic_load(hrow + ks * 8 + quad * 2 + 1,
                                           __ATOMIC_RELAXED, __HIP_MEMORY_SCOPE_AGENT);
            }
            f32x4 acc[4];
#pragma unroll
            for (int ct = 0; ct < 4; ct++) acc[ct] = (f32x4){0.f, 0.f, 0.f, 0.f};
#pragma unroll
            for (int ks = 0; ks < 8; ks++) {
                union { bf16x8 v; unsigned long long q[2]; } af;
                af.q[0] = a0[ks]; af.q[1] = a1[ks];
#pragma unroll
                for (int ct = 0; ct < 4; ct++)
                    acc[ct] = __builtin_amdgcn_mfma_f32_16x16x32_bf16(
                        af.v, Bf[ct][ks], acc[ct], 0, 0, 0);
            }
#pragma unroll
            for (int ct = 0; ct < 4; ct++)
#pragma unroll
                for (int r = 0; r < 4; r++)
                    G[w * 16 + quad * 4 + r][ct * 16 + n] = acc[ct][r];
        }
        __syncthreads();
        {
            const float4* Gp = (const float4*)&G[rr][us * 4];
            unsigned long long hpack = 0ull;
            float hout[4];
#pragma unroll
            for (int p = 0; p < 4; p++) {
                float4 gv = Gp[p];
                float gi = gv.x + xv[p].x;
                float gf = gv.y + xv[p].y;
                float gg = gv.z + xv[p].z;
                float go = gv.w + xv[p].w;
                float cn = sigm(gf) * cr[p] + sigm(gi) * tanhf(gg);
                float hn = sigm(go) * tanhf(cn);
                cr[p] = cn; hout[p] = hn;
                hpack |= ((unsigned long long)f2bf(hn)) << (16 * p);
            }
            __hip_atomic_store((unsigned long long*)(hq + (size_t)grow_e * 256 + u0 + us),
                               hpack, __ATOMIC_RELAXED, __HIP_MEMORY_SCOPE_AGENT);
            *(float4*)(documents + (size_t)(seq * 10 + dpos) * 512 + doff + u0 + us) =
                *(float4*)hout;
        }
        if (t < 9) {
            const float* xb = !bwd ? xw + ((size_t)seq * 10 + t + 1) * 2048
                                   : xw + ((size_t)seq * 10 + 8 - t) * 2048 + 1024;
            const float4* xp = (const float4*)(xb + (size_t)(u0 + us) * 4);
            xv[0] = xp[0]; xv[1] = xp[1]; xv[2] = xp[2]; xv[3] = xp[3];
            group_barrier(cnt, 16u * (unsigned)(t + 1));
        }
    }
}

// SourceBias: biasedBf[t] = bf16(tanh(sen[t] @ trans[u] + sb_bias[u]))
__global__ __launch_bounds__(256) void source_bias(
    const float* __restrict__ sentences, const int* __restrict__ urls,
    const float* __restrict__ trans, const float* __restrict__ sb_bias,
    unsigned* __restrict__ biasedBf)
{
    const int tkn = blockIdx.x;
    const int u = urls[tkn];
    const float2* Tm = (const float2*)(trans + (size_t)u * 512 * 512);
    __shared__ float sv[512];
    for (int i = threadIdx.x; i < 512; i += 256) sv[i] = sentences[(size_t)tkn * 512 + i];
    __syncthreads();
    const int e = threadIdx.x;               // column pair (2e, 2e+1)
    float ax = 0.f, ay = 0.f;
#pragma unroll 4
    for (int d = 0; d < 512; d++) {
        float s = sv[d];
        float2 tv = Tm[(size_t)d * 256 + e];
        ax += s * tv.x; ay += s * tv.y;
    }
    const float2 bv = ((const float2*)(sb_bias + (size_t)u * 512))[e];
    float x = tanhf(ax + bv.x), y = tanhf(ay + bv.y);
    biasedBf[(size_t)tkn * 256 + e] = (unsigned)f2bf(x) | ((unsigned)f2bf(y) << 16);
}

// v[b,d] = sum_e attn_W[d,e] * heading[b,e]; block per b
__global__ __launch_bounds__(256) void attn_v(
    const float* __restrict__ W, const float* __restrict__ headings,
    float* __restrict__ v)
{
    const int b = blockIdx.x;
    __shared__ float hh[512];
    for (int i = threadIdx.x; i < 512; i += 256) hh[i] = headings[(size_t)b * 512 + i];
    __syncthreads();
    for (int d = threadIdx.x; d < 512; d += 256) {
        float a = 0.f;
        const float* wr = W + (size_t)d * 512;
        for (int e = 0; e < 512; e++) a += wr[e] * hh[e];
        v[(size_t)b * 512 + d] = a;
    }
}

// scores -> softmax -> doc_rep -> both MLP heads; block per batch element
__global__ __launch_bounds__(256) void attn_heads(
    const float* __restrict__ documents, const float* __restrict__ v,
    const float* __restrict__ attn_b,
    const float* __restrict__ bW1, const float* __restrict__ bb1,
    const float* __restrict__ bW2, const float* __restrict__ bb2,
    const float* __restrict__ tW1, const float* __restrict__ tb1,
    const float* __restrict__ tW2, const float* __restrict__ tb2,
    float* __restrict__ out)
{
    const int b = blockIdx.x, tid = threadIdx.x;
    const int lane = tid & 63, wv_ = tid >> 6;
    __shared__ float vv[512], dr[512], h1s[256], t1s[256], sw[12], lg[5];
    for (int i = tid; i < 512; i += 256) vv[i] = v[(size_t)b * 512 + i];
    __syncthreads();
    for (int q = 0; q < 3; q++) {
        int s = q * 4 + wv_;
        float p = 0.f;
        if (s < 10) {
            const float* dp = documents + (size_t)(b * 10 + s) * 512;
            for (int d = lane; d < 512; d += 64) p += dp[d] * vv[d];
        }
#pragma unroll
        for (int off = 32; off > 0; off >>= 1) p += __shfl_down(p, off, 64);
        if (s < 10 && lane == 0) sw[s] = p + attn_b[0];
    }
    __syncthreads();
    if (tid == 0) {
        float mx = sw[0];
        for (int s = 1; s < 10; s++) mx = fmaxf(mx, sw[s]);
        float sum = 0.f;
        for (int s = 0; s < 10; s++) { sw[s] = expf(sw[s] - mx); sum += sw[s]; }
        for (int s = 0; s < 10; s++) sw[s] /= sum;
    }
    __syncthreads();
    for (int d = tid; d < 512; d += 256) {
        float a = 0.f;
#pragma unroll
        for (int s = 0; s < 10; s++) a += sw[s] * documents[(size_t)(b * 10 + s) * 512 + d];
        dr[d] = a;
    }
    __syncthreads();
    {
        float a = bb1[tid], a2 = tb1[tid];
        const float* w1 = bW1 + (size_t)tid * 512;
        const float* w2 = tW1 + (size_t)tid * 512;
        for (int k = 0; k < 512; k++) { float x = dr[k]; a += x * w1[k]; a2 += x * w2[k]; }
        h1s[tid] = tanhf(a); t1s[tid] = tanhf(a2);
    }
    __syncthreads();
    if (tid < 5) {
        float a = bb2[tid];
        const float* wp = bW2 + (size_t)tid * 256;
        for (int k = 0; k < 256; k++) a += h1s[k] * wp[k];
        lg[tid] = tanhf(a);
    }
    if (tid == 32) {
        float a = tb2[0];
        for (int k = 0; k < 256; k++) a += t1s[k] * tW2[k];
        out[320 + b] = 1.f / (1.f + expf(-tanhf(a)));
    }
    __syncthreads();
    if (tid == 0) {
        float mx = lg[0];
        for (int j = 1; j < 5; j++) mx = fmaxf(mx, lg[j]);
        float sum = 0.f, e[5];
        for (int j = 0; j < 5; j++) { e[j] = expf(lg[j] - mx); sum += e[j]; }
        for (int j = 0; j < 5; j++) out[b * 5 + j] = e[j] / sum;
    }
}

extern "C" void kernel_launch(void* const* d_in, const int* in_sizes, int n_in,
                              void* d_out, int out_size, void* d_ws, size_t ws_size,
                              hipStream_t stream)
{
    (void)in_sizes; (void)n_in; (void)out_size; (void)ws_size;
    const int*   input_ids = (const int*)d_in[0];
    const int*   urls      = (const int*)d_in[1];
    const int*   titles    = (const int*)d_in[2];
    const float* emb       = (const float*)d_in[3];
    const float* sen_wih_f = (const float*)d_in[4];
    const float* sen_whh_f = (const float*)d_in[5];
    const float* sen_b_f   = (const float*)d_in[6];
    const float* sen_wih_b = (const float*)d_in[7];
    const float* sen_whh_b = (const float*)d_in[8];
    const float* sen_b_b   = (const float*)d_in[9];
    const float* trans     = (const float*)d_in[10];
    const float* sb_bias   = (const float*)d_in[11];
    const float* doc_wih_f = (const float*)d_in[12];
    const float* doc_whh_f = (const float*)d_in[13];
    const float* doc_b_f   = (const float*)d_in[14];
    const float* doc_wih_b = (const float*)d_in[15];
    const float* doc_whh_b = (const float*)d_in[16];
    const float* doc_b_b   = (const float*)d_in[17];
    const float* attn_W    = (const float*)d_in[18];
    const float* attn_b    = (const float*)d_in[19];
    const float* bias_W1   = (const float*)d_in[20];
    const float* bias_b1   = (const float*)d_in[21];
    const float* bias_W2   = (const float*)d_in[22];
    const float* bias_b2   = (const float*)d_in[23];
    const float* truth_W1  = (const float*)d_in[24];
    const float* truth_b1  = (const float*)d_in[25];
    const float* truth_W2  = (const float*)d_in[26];
    const float* truth_b2  = (const float*)d_in[27];
    float* out = (float*)d_out;

    // ------------------------------------------------------------------
    // Workspace layout with lifetime overlays (offsets in FLOATS).
    // Slot A = xw_all [0 .. 41,287,680): live D2–D3. After D3 overlaid by
    //   biasedBf(+0), xw_doc(+163,840), documents(+1,474,560), vbuf(+1,802,240).
    // Slot B = Abf [41,287,680 .. +3,225,600): live D1–D2. After D2 overlaid by
    //   sentences(+0), headings(+327,680), hbA(+360,448), hbB(+540,672),
    //   hdA(+720,896), hdB(+737,280), bars(+753,664).
    // Slot C = Wsen [44,513,280 .. +327,680). Slot D = Wdoc [44,840,960 .. +524,288).
    // ------------------------------------------------------------------
    float* ws = (float*)d_ws;
    float* xw_all      = ws;
    float* xw_head     = xw_all + (size_t)19200 * 2048;
    unsigned* biasedBf = (unsigned*)(ws + 0);
    float* xw_doc      = ws + 163840;
    float* documents   = ws + 1474560;
    float* vbuf        = ws + 1802240;

    float* slotB       = ws + 41287680;
    unsigned* Abf      = (unsigned*)slotB;
    float* sentences   = slotB;
    float* headings    = slotB + 327680;
    unsigned short* hbA = (unsigned short*)(slotB + 360448);
    unsigned short* hbB = (unsigned short*)(slotB + 540672);
    unsigned short* hdA = (unsigned short*)(slotB + 720896);
    unsigned short* hdB = (unsigned short*)(slotB + 737280);
    unsigned* barsS    = (unsigned*)(slotB + 753664);   // 22 counters, 16-uint stride
    unsigned* barsD    = barsS + 22 * 16;               // 2 counters

    unsigned* Wsen     = (unsigned*)(ws + 44513280);
    unsigned* Wdoc     = (unsigned*)(ws + 44840960);

    dim3 blk(256);

    // D1: gather + bf16 casts
    prep_cast<<<dim3((N0 + N1 + N2 + 255) / 256), blk, 0, stream>>>(
        input_ids, titles, emb, sen_wih_f, sen_wih_b, doc_wih_f, doc_wih_b,
        Abf, Wsen, Wdoc);

    // D2: sentence+title input projection
    proj_mfma<<<dim3(158, 16), blk, 0, stream>>>(
        (const unsigned short*)Abf, 20160, 320,
        (const unsigned short*)Wsen, sen_b_f, sen_b_b, xw_all);

    // Zero-init h states + barrier counters (slot B dead after D2)
    hipMemsetAsync(hbA, 0, (size_t)1408 * 256 * 2, stream);
    hipMemsetAsync(hdA, 0, (size_t)128 * 256 * 2, stream);
    hipMemsetAsync(barsS, 0, (22 + 2) * 16 * sizeof(unsigned), stream);

    // D3: persistent sentence/heading BiLSTM
    lstm_sen<<<dim3(16, 22), blk, 0, stream>>>(
        xw_all, xw_head, sen_whh_f, sen_whh_b, hbA, hbB,
        sentences, headings, barsS);

    // D4: SourceBias
    source_bias<<<dim3(640), blk, 0, stream>>>(sentences, urls, trans, sb_bias, biasedBf);

    // D5: document input projection
    proj_mfma<<<dim3(5, 16), blk, 0, stream>>>(
        (const unsigned short*)biasedBf, 640, 512,
        (const unsigned short*)Wdoc, doc_b_f, doc_b_b, xw_doc);

    // D6: persistent document BiLSTM
    lstm_doc<<<dim3(16, 2), blk, 0, stream>>>(
        xw_doc, doc_whh_f, doc_whh_b, hdA, hdB, documents, barsD);

    // D7/D8: attention + heads
    attn_v<<<dim3(64), blk, 0, stream>>>(attn_W, headings, vbuf);
    attn_heads<<<dim3(64), blk, 0, stream>>>(documents, vbuf, attn_b,
                                             bias_W1, bias_b1, bias_W2, bias_b2,
                                             truth_W1, truth_b1, truth_W2, truth_b2,
                                             out);
}

// Round 3
// 594.546 us; speedup vs baseline: 1.2495x; 1.2495x over previous
//
#include <hip/hip_runtime.h>
#include <cstddef>

typedef short bf16x8 __attribute__((ext_vector_type(8)));
typedef float f32x4 __attribute__((ext_vector_type(4)));

__device__ __forceinline__ float sigm(float x) { return 1.f / (1.f + expf(-x)); }

// f32 -> bf16 (round to nearest even)
__device__ __forceinline__ unsigned short f2bf(float f) {
    union { float f; unsigned u; } v; v.f = f;
    return (unsigned short)((v.u + 0x7FFFu + ((v.u >> 16) & 1u)) >> 16);
}

// ============================================================================
// prep_cast: one pass producing all bf16 operands.
//  region0: Abf[20160][320bf16]  = emb rows gathered by input_ids(19200)+titles(960)
//  region1: Wsen[2048][320bf16]  = [sen_wih_f | sen_wih_b] (K 300 -> 320 zero-pad)
//  region2: Wdoc[2048][512bf16]  = [doc_wih_f | doc_wih_b]
// ============================================================================
#define N0 (20160 * 160)
#define N1 (2048 * 160)
#define N2 (2048 * 256)

__global__ __launch_bounds__(256) void prep_cast(
    const int* __restrict__ ids, const int* __restrict__ titles,
    const float* __restrict__ emb,
    const float* __restrict__ swf, const float* __restrict__ swb,
    const float* __restrict__ dwf, const float* __restrict__ dwb,
    unsigned* __restrict__ Abf, unsigned* __restrict__ Wsen,
    unsigned* __restrict__ Wdoc)
{
    int idx = blockIdx.x * 256 + threadIdx.x;
    if (idx < N0) {
        int row = idx / 160, kk = idx - row * 160;
        int id = (row < 19200) ? ids[row] : titles[row - 19200];
        float a = 0.f, b = 0.f;
        if (kk < 150) {
            const float* s = emb + (size_t)id * 300 + kk * 2;
            a = s[0]; b = s[1];
        }
        Abf[idx] = (unsigned)f2bf(a) | ((unsigned)f2bf(b) << 16);
    } else if (idx < N0 + N1) {
        int j = idx - N0;
        int row = j / 160, kk = j - row * 160;
        const float* base = (row < 1024) ? swf + (size_t)row * 300
                                         : swb + (size_t)(row - 1024) * 300;
        float a = 0.f, b = 0.f;
        if (kk < 150) { a = base[kk * 2]; b = base[kk * 2 + 1]; }
        Wsen[j] = (unsigned)f2bf(a) | ((unsigned)f2bf(b) << 16);
    } else if (idx < N0 + N1 + N2) {
        int j = idx - N0 - N1;
        int row = j >> 8, kk = j & 255;
        const float* base = (row < 1024) ? dwf + (size_t)row * 512
                                         : dwb + (size_t)(row - 1024) * 512;
        Wdoc[j] = (unsigned)f2bf(base[kk * 2]) | ((unsigned)f2bf(base[kk * 2 + 1]) << 16);
    }
}

// ============================================================================
// prep_whh: cast LSTM hidden weights to bf16, row-major [dir][1024][256].
//  WS: sen (f,b), WD: doc (f,b). 2 * 131072 u32 each.
// ============================================================================
__global__ __launch_bounds__(256) void prep_whh(
    const float* __restrict__ swf, const float* __restrict__ swb,
    const float* __restrict__ dwf, const float* __restrict__ dwb,
    unsigned* __restrict__ WS, unsigned* __restrict__ WD)
{
    int idx = blockIdx.x * 256 + threadIdx.x;   // 0 .. 524287
    const float* src; unsigned* dst;
    if (idx < 262144) {
        int j = idx; int dir = j >> 17; int rem = j & 131071;
        src = (dir ? swb : swf) + ((size_t)(rem >> 7) * 256 + (rem & 127) * 2);
        dst = WS + j;
    } else {
        int j = idx - 262144; int dir = j >> 17; int rem = j & 131071;
        src = (dir ? dwb : dwf) + ((size_t)(rem >> 7) * 256 + (rem & 127) * 2);
        dst = WD + j;
    }
    *dst = (unsigned)f2bf(src[0]) | ((unsigned)f2bf(src[1]) << 16);
}

// ============================================================================
// proj_mfma: out[M][2048] = Abf[M][Kp] @ Wbf^T + bias, output GATE-INTERLEAVED:
//   col = half*1024 + unit*4 + gate   (unit 0..255, gate 0..3 = i,f,g,o)
// ============================================================================
__global__ __launch_bounds__(256) void proj_mfma(
    const unsigned short* __restrict__ Abf, int M, int Kp,
    const unsigned short* __restrict__ Wbf,
    const float* __restrict__ bf_, const float* __restrict__ bb_,
    float* __restrict__ out)
{
    __shared__ unsigned short As[128 * 40];   // pitch 80B (16B aligned)
    __shared__ unsigned short Ws[128 * 40];
    const int tid  = threadIdx.x;
    const int lane = tid & 63;
    const int w    = tid >> 6;
    const int n    = lane & 15;
    const int quad = lane >> 4;
    const int bm   = blockIdx.x * 128;
    const int by   = blockIdx.y;              // 0..15
    const int half = by >> 3;
    const int ug32 = (by & 7) * 32;
    const unsigned short* Wb = Wbf + (size_t)half * 1024 * Kp;
    const float* biasp = half ? bb_ : bf_;

    f32x4 acc[2][8];
#pragma unroll
    for (int rt = 0; rt < 2; rt++)
#pragma unroll
        for (int ct = 0; ct < 8; ct++) acc[rt][ct] = (f32x4){0.f, 0.f, 0.f, 0.f};

    const int chunks = Kp >> 5;
    for (int kc = 0; kc < chunks; kc++) {
        const int k0 = kc * 32;
#pragma unroll
        for (int j = 0; j < 2; j++) {
            int idx = j * 256 + tid;
            int arow = idx >> 2, qq = idx & 3;
            int grow = bm + arow; if (grow >= M) grow = M - 1;
            *(uint4*)&As[arow * 40 + qq * 8] =
                *(const uint4*)(Abf + (size_t)grow * Kp + k0 + qq * 8);
            int cc = idx >> 2;
            int wrow = (cc >> 5) * 256 + ug32 + (cc & 31);   // gate=cc>>5, unit
            *(uint4*)&Ws[cc * 40 + qq * 8] =
                *(const uint4*)(Wb + (size_t)wrow * Kp + k0 + qq * 8);
        }
        __syncthreads();
        bf16x8 Aq[2], Bq[8];
#pragma unroll
        for (int rt = 0; rt < 2; rt++)
            Aq[rt] = *(const bf16x8*)&As[((w * 2 + rt) * 16 + n) * 40 + quad * 8];
#pragma unroll
        for (int ct = 0; ct < 8; ct++)
            Bq[ct] = *(const bf16x8*)&Ws[(ct * 16 + n) * 40 + quad * 8];
#pragma unroll
        for (int rt = 0; rt < 2; rt++)
#pragma unroll
            for (int ct = 0; ct < 8; ct++)
                acc[rt][ct] = __builtin_amdgcn_mfma_f32_16x16x32_bf16(
                    Aq[rt], Bq[ct], acc[rt][ct], 0, 0, 0);
        __syncthreads();
    }

#pragma unroll
    for (int s = 0; s < 2; s++) {
        const int uL = s * 16 + n;
        float b0 = biasp[ug32 + uL];
        float b1 = biasp[256 + ug32 + uL];
        float b2 = biasp[512 + ug32 + uL];
        float b3 = biasp[768 + ug32 + uL];
#pragma unroll
        for (int rt = 0; rt < 2; rt++) {
#pragma unroll
            for (int r = 0; r < 4; r++) {
                int row = bm + (w * 2 + rt) * 16 + quad * 4 + r;
                if (row >= M) continue;
                float4 o;
                o.x = acc[rt][0 + s][r] + b0;
                o.y = acc[rt][2 + s][r] + b1;
                o.z = acc[rt][4 + s][r] + b2;
                o.w = acc[rt][6 + s][r] + b3;
                *(float4*)(out + (size_t)row * 2048 + half * 1024 + (ug32 + uL) * 4) = o;
            }
        }
    }
}

// ---------------------------------------------------------------------------
// pair_sync: 2 blocks, MONOTONIC counter, ALL RELAXED agent atomics.
// __syncthreads drains each thread's h-stores (vmcnt) before arrival.
// ---------------------------------------------------------------------------
__device__ __forceinline__ void pair_sync(unsigned* cnt, unsigned target) {
    __syncthreads();
    if (threadIdx.x == 0) {
        __hip_atomic_fetch_add(cnt, 1u, __ATOMIC_RELAXED, __HIP_MEMORY_SCOPE_AGENT);
        while (__hip_atomic_load(cnt, __ATOMIC_RELAXED, __HIP_MEMORY_SCOPE_AGENT) < target)
            __builtin_amdgcn_s_sleep(1);
    }
    __syncthreads();
}

__device__ __forceinline__ const float* sen_xbase(
    const float* xw, const float* xw_head, int grow_e, int t)
{
    if (grow_e < 640)       return xw + ((size_t)grow_e * 30 + t) * 2048;
    else if (grow_e < 1280) return xw + ((size_t)(grow_e - 640) * 30 + 29 - t) * 2048 + 1024;
    else if (grow_e < 1344) return xw_head + ((size_t)(grow_e - 1280) * 15 + t) * 2048;
    else                    return xw_head + ((size_t)(grow_e - 1344) * 15 + 14 - t) * 2048 + 1024;
}

// ============================================================================
// lstm_sen2: persistent BiLSTM. 88 groups of 16 rows; each group = a PAIR of
// 512-thread blocks, each owning 128 of the 256 hidden units (half of Whh in
// registers). Per step: own h-half stays in LDS; partner half = one 4 KB L2
// round-trip gated by a 2-block monotonic counter (pairs co-located per XCD
// via blockIdx swizzle: phys i and i+8 share an XCD under round-robin).
// Rows: 0..639 sen-fwd | 640..1279 sen-bwd | 1280..1343 head-f | 1344..1407 head-b.
// ============================================================================
__global__ __launch_bounds__(512, 2) void lstm_sen2(
    const float* __restrict__ xw, const float* __restrict__ xw_head,
    const unsigned short* __restrict__ WhhBf,     // [2][1024][256] bf16
    unsigned short* hbA, unsigned short* hbB,
    float* __restrict__ sentences, float* __restrict__ headings,
    unsigned* bars)
{
    const int tid  = threadIdx.x;
    const int lane = tid & 63;
    const int w    = tid >> 6;          // 0..7 (wave)
    const int n    = lane & 15;
    const int quad = lane >> 4;
    const int phys = blockIdx.x;        // 0..175
    const int g    = (phys & 7) + (phys >> 4) * 8;   // 0..87 (pair group)
    const int p    = (phys >> 3) & 1;                // unit-half
    const int r0   = g * 16;
    const bool bwd  = (r0 >= 640 && r0 < 1280) || (r0 >= 1344);
    const bool head = (r0 >= 1280);
    const int tEnd = head ? 15 : 30;
    unsigned* cnt = bars + g * 16;      // 64B-separated counters
    const unsigned short* Wd = WhhBf + (bwd ? (size_t)262144 : 0);

    __shared__ unsigned short Hs[2][16][264];   // pitch 528B: 2-way-bank-safe
    __shared__ float G[16][516];                // pitch 2064B

    // B fragments: wave w owns local cols w*64 + ct*16 + n
    // local col c -> unit = p*128 + w*16 + (c>>2), gate = c&3; Wrow = gate*256+unit
    bf16x8 Bf[4][8];
#pragma unroll
    for (int ct = 0; ct < 4; ct++) {
        const int c    = ct * 16 + n;
        const int unit = p * 128 + w * 16 + (c >> 2);
        const int wrow = (c & 3) * 256 + unit;
        const unsigned short* wr = Wd + (size_t)wrow * 256;
#pragma unroll
        for (int ks = 0; ks < 8; ks++)
            Bf[ct][ks] = *(const bf16x8*)(wr + ks * 32 + quad * 8);
    }

    // zero h(t=0)
    for (int i = tid; i < 16 * 264; i += 512) ((unsigned short*)Hs[0])[i] = 0;

    const int rE  = tid & 15;            // row within group
    const int iE  = tid >> 4;            // 0..31
    const int ug4 = p * 128 + iE * 4;    // global unit base (4 units/thread)
    const int grow_e = r0 + rE;
    float cr[4] = {0.f, 0.f, 0.f, 0.f};

    float4 xv[4];
    {
        const float4* xp = (const float4*)(sen_xbase(xw, xw_head, grow_e, 0)
                                           + (size_t)ug4 * 4);
        xv[0] = xp[0]; xv[1] = xp[1]; xv[2] = xp[2]; xv[3] = xp[3];
    }
    __syncthreads();

    for (int t = 0; t < tEnd; t++) {
        const int cur = t & 1;
        unsigned short* hq = (t & 1) ? hbA : hbB;

        // ---- hidden GEMM: G[0..15][own 512 cols] = h(t) @ Whh-half ----
        {
            bf16x8 Af[8];
#pragma unroll
            for (int ks = 0; ks < 8; ks++)
                Af[ks] = *(const bf16x8*)&Hs[cur][n][ks * 32 + quad * 8];
            f32x4 acc[4];
#pragma unroll
            for (int ct = 0; ct < 4; ct++) acc[ct] = (f32x4){0.f, 0.f, 0.f, 0.f};
#pragma unroll
            for (int ks = 0; ks < 8; ks++)
#pragma unroll
                for (int ct = 0; ct < 4; ct++)
                    acc[ct] = __builtin_amdgcn_mfma_f32_16x16x32_bf16(
                        Af[ks], Bf[ct][ks], acc[ct], 0, 0, 0);
#pragma unroll
            for (int ct = 0; ct < 4; ct++)
#pragma unroll
                for (int r = 0; r < 4; r++)
                    G[quad * 4 + r][w * 64 + ct * 16 + n] = acc[ct][r];
        }
        __syncthreads();

        // ---- gate epilogue: 4 (row,unit) pairs per thread ----
        {
            float* fdst = nullptr;
            if (!head) {
                if (t == 29) fdst = sentences +
                    (size_t)(bwd ? grow_e - 640 : grow_e) * 512 + (bwd ? 256 : 0);
            } else {
                if (t == 14) fdst = headings +
                    (size_t)(grow_e - (bwd ? 1344 : 1280)) * 512 + (bwd ? 256 : 0);
            }
            const float4* Gp = (const float4*)&G[rE][iE * 16];
            unsigned long long hpack = 0ull;
            float hout[4];
#pragma unroll
            for (int q2 = 0; q2 < 4; q2++) {
                float4 gv = Gp[q2];
                float4 xq = xv[q2];
                float gi = gv.x + xq.x;
                float gf = gv.y + xq.y;
                float gg = gv.z + xq.z;
                float go = gv.w + xq.w;
                float cn = sigm(gf) * cr[q2] + sigm(gi) * tanhf(gg);
                float hn = sigm(go) * tanhf(cn);
                cr[q2] = cn; hout[q2] = hn;
                hpack |= ((unsigned long long)f2bf(hn)) << (16 * q2);
            }
            const int nxt = cur ^ 1;
            *(unsigned long long*)&Hs[nxt][rE][ug4] = hpack;   // own half -> LDS
            __hip_atomic_store((unsigned long long*)(hq + (size_t)grow_e * 256 + ug4),
                               hpack, __ATOMIC_RELAXED, __HIP_MEMORY_SCOPE_AGENT);
            if (fdst) *(float4*)(fdst + ug4) = *(float4*)hout;
        }

        if (t + 1 < tEnd) {
            // prefetch next step's xw BEFORE the sync wait (h-independent)
            const float4* xp = (const float4*)(sen_xbase(xw, xw_head, grow_e, t + 1)
                                               + (size_t)ug4 * 4);
            xv[0] = xp[0]; xv[1] = xp[1]; xv[2] = xp[2]; xv[3] = xp[3];
            pair_sync(cnt, 2u * (unsigned)(t + 1));
            // partner half -> Hs[nxt]: one 8B chunk per thread (16 rows x 32)
            {
                const int nxt   = cur ^ 1;
                const int row   = tid >> 5;
                const int chunk = tid & 31;
                const int pp    = p ^ 1;
                unsigned long long v = __hip_atomic_load(
                    (const unsigned long long*)(hq + (size_t)(r0 + row) * 256
                                                + pp * 128 + chunk * 4),
                    __ATOMIC_RELAXED, __HIP_MEMORY_SCOPE_AGENT);
                *(unsigned long long*)&Hs[nxt][row][pp * 128 + chunk * 4] = v;
            }
            __syncthreads();
        }
    }
}

// ============================================================================
// lstm_doc2: same pair structure. 8 groups of 16 rows (docs), 10 steps.
// Rows 0..63 fwd (doc=row), 64..127 bwd (doc=row-64). Grid 16 x 512.
// ============================================================================
__global__ __launch_bounds__(512, 2) void lstm_doc2(
    const float* __restrict__ xw,
    const unsigned short* __restrict__ WhhBf,     // [2][1024][256] bf16
    unsigned short* hdA, unsigned short* hdB,
    float* __restrict__ documents,
    unsigned* bars)
{
    const int tid  = threadIdx.x;
    const int lane = tid & 63;
    const int w    = tid >> 6;
    const int n    = lane & 15;
    const int quad = lane >> 4;
    const int phys = blockIdx.x;        // 0..15
    const int g    = phys & 7;          // 0..7
    const int p    = (phys >> 3) & 1;
    const int r0   = g * 16;
    const bool bwd = (r0 >= 64);
    unsigned* cnt = bars + g * 16;
    const unsigned short* Wd = WhhBf + (bwd ? (size_t)262144 : 0);

    __shared__ unsigned short Hs[2][16][264];
    __shared__ float G[16][516];

    bf16x8 Bf[4][8];
#pragma unroll
    for (int ct = 0; ct < 4; ct++) {
        const int c    = ct * 16 + n;
        const int unit = p * 128 + w * 16 + (c >> 2);
        const int wrow = (c & 3) * 256 + unit;
        const unsigned short* wr = Wd + (size_t)wrow * 256;
#pragma unroll
        for (int ks = 0; ks < 8; ks++)
            Bf[ct][ks] = *(const bf16x8*)(wr + ks * 32 + quad * 8);
    }

    for (int i = tid; i < 16 * 264; i += 512) ((unsigned short*)Hs[0])[i] = 0;

    const int rE  = tid & 15;
    const int iE  = tid >> 4;
    const int ug4 = p * 128 + iE * 4;
    const int grow_e = r0 + rE;
    const int seq = bwd ? grow_e - 64 : grow_e;     // doc index
    float cr[4] = {0.f, 0.f, 0.f, 0.f};

    float4 xv[4];
    {
        const float* xb = !bwd ? xw + ((size_t)seq * 10 + 0) * 2048
                               : xw + ((size_t)seq * 10 + 9) * 2048 + 1024;
        const float4* xp = (const float4*)(xb + (size_t)ug4 * 4);
        xv[0] = xp[0]; xv[1] = xp[1]; xv[2] = xp[2]; xv[3] = xp[3];
    }
    __syncthreads();

    for (int t = 0; t < 10; t++) {
        const int cur = t & 1;
        unsigned short* hq = (t & 1) ? hdA : hdB;
        const int dpos = !bwd ? t : 9 - t;
        const int doff = !bwd ? 0 : 256;

        {
            bf16x8 Af[8];
#pragma unroll
            for (int ks = 0; ks < 8; ks++)
                Af[ks] = *(const bf16x8*)&Hs[cur][n][ks * 32 + quad * 8];
            f32x4 acc[4];
#pragma unroll
            for (int ct = 0; ct < 4; ct++) acc[ct] = (f32x4){0.f, 0.f, 0.f, 0.f};
#pragma unroll
            for (int ks = 0; ks < 8; ks++)
#pragma unroll
                for (int ct = 0; ct < 4; ct++)
                    acc[ct] = __builtin_amdgcn_mfma_f32_16x16x32_bf16(
                        Af[ks], Bf[ct][ks], acc[ct], 0, 0, 0);
#pragma unroll
            for (int ct = 0; ct < 4; ct++)
#pragma unroll
                for (int r = 0; r < 4; r++)
                    G[quad * 4 + r][w * 64 + ct * 16 + n] = acc[ct][r];
        }
        __syncthreads();

        {
            const float4* Gp = (const float4*)&G[rE][iE * 16];
            unsigned long long hpack = 0ull;
            float hout[4];
#pragma unroll
            for (int q2 = 0; q2 < 4; q2++) {
                float4 gv = Gp[q2];
                float gi = gv.x + xv[q2].x;
                float gf = gv.y + xv[q2].y;
                float gg = gv.z + xv[q2].z;
                float go = gv.w + xv[q2].w;
                float cn = sigm(gf) * cr[q2] + sigm(gi) * tanhf(gg);
                float hn = sigm(go) * tanhf(cn);
                cr[q2] = cn; hout[q2] = hn;
                hpack |= ((unsigned long long)f2bf(hn)) << (16 * q2);
            }
            const int nxt = cur ^ 1;
            *(unsigned long long*)&Hs[nxt][rE][ug4] = hpack;
            __hip_atomic_store((unsigned long long*)(hq + (size_t)grow_e * 256 + ug4),
                               hpack, __ATOMIC_RELAXED, __HIP_MEMORY_SCOPE_AGENT);
            *(float4*)(documents + (size_t)(seq * 10 + dpos) * 512 + doff + ug4) =
                *(float4*)hout;
        }

        if (t < 9) {
            const float* xb = !bwd ? xw + ((size_t)seq * 10 + t + 1) * 2048
                                   : xw + ((size_t)seq * 10 + 8 - t) * 2048 + 1024;
            const float4* xp = (const float4*)(xb + (size_t)ug4 * 4);
            xv[0] = xp[0]; xv[1] = xp[1]; xv[2] = xp[2]; xv[3] = xp[3];
            pair_sync(cnt, 2u * (unsigned)(t + 1));
            {
                const int nxt   = cur ^ 1;
                const int row   = tid >> 5;
                const int chunk = tid & 31;
                const int pp    = p ^ 1;
                unsigned long long v = __hip_atomic_load(
                    (const unsigned long long*)(hq + (size_t)(r0 + row) * 256
                                                + pp * 128 + chunk * 4),
                    __ATOMIC_RELAXED, __HIP_MEMORY_SCOPE_AGENT);
                *(unsigned long long*)&Hs[nxt][row][pp * 128 + chunk * 4] = v;
            }
            __syncthreads();
        }
    }
}

// SourceBias: biasedBf[t] = bf16(tanh(sen[t] @ trans[u] + sb_bias[u]))
__global__ __launch_bounds__(256) void source_bias(
    const float* __restrict__ sentences, const int* __restrict__ urls,
    const float* __restrict__ trans, const float* __restrict__ sb_bias,
    unsigned* __restrict__ biasedBf)
{
    const int tkn = blockIdx.x;
    const int u = urls[tkn];
    const float2* Tm = (const float2*)(trans + (size_t)u * 512 * 512);
    __shared__ float sv[512];
    for (int i = threadIdx.x; i < 512; i += 256) sv[i] = sentences[(size_t)tkn * 512 + i];
    __syncthreads();
    const int e = threadIdx.x;               // column pair (2e, 2e+1)
    float ax = 0.f, ay = 0.f;
#pragma unroll 4
    for (int d = 0; d < 512; d++) {
        float s = sv[d];
        float2 tv = Tm[(size_t)d * 256 + e];
        ax += s * tv.x; ay += s * tv.y;
    }
    const float2 bv = ((const float2*)(sb_bias + (size_t)u * 512))[e];
    float x = tanhf(ax + bv.x), y = tanhf(ay + bv.y);
    biasedBf[(size_t)tkn * 256 + e] = (unsigned)f2bf(x) | ((unsigned)f2bf(y) << 16);
}

// v[b,d] = sum_e attn_W[d,e] * heading[b,e]; block per b
__global__ __launch_bounds__(256) void attn_v(
    const float* __restrict__ W, const float* __restrict__ headings,
    float* __restrict__ v)
{
    const int b = blockIdx.x;
    __shared__ float hh[512];
    for (int i = threadIdx.x; i < 512; i += 256) hh[i] = headings[(size_t)b * 512 + i];
    __syncthreads();
    for (int d = threadIdx.x; d < 512; d += 256) {
        float a = 0.f;
        const float* wr = W + (size_t)d * 512;
        for (int e = 0; e < 512; e++) a += wr[e] * hh[e];
        v[(size_t)b * 512 + d] = a;
    }
}

// scores -> softmax -> doc_rep -> both MLP heads; block per batch element
__global__ __launch_bounds__(256) void attn_heads(
    const float* __restrict__ documents, const float* __restrict__ v,
    const float* __restrict__ attn_b,
    const float* __restrict__ bW1, const float* __restrict__ bb1,
    const float* __restrict__ bW2, const float* __restrict__ bb2,
    const float* __restrict__ tW1, const float* __restrict__ tb1,
    const float* __restrict__ tW2, const float* __restrict__ tb2,
    float* __restrict__ out)
{
    const int b = blockIdx.x, tid = threadIdx.x;
    const int lane = tid & 63, wv_ = tid >> 6;
    __shared__ float vv[512], dr[512], h1s[256], t1s[256], sw[12], lg[5];
    for (int i = tid; i < 512; i += 256) vv[i] = v[(size_t)b * 512 + i];
    __syncthreads();
    for (int q = 0; q < 3; q++) {
        int s = q * 4 + wv_;
        float p = 0.f;
        if (s < 10) {
            const float* dp = documents + (size_t)(b * 10 + s) * 512;
            for (int d = lane; d < 512; d += 64) p += dp[d] * vv[d];
        }
#pragma unroll
        for (int off = 32; off > 0; off >>= 1) p += __shfl_down(p, off, 64);
        if (s < 10 && lane == 0) sw[s] = p + attn_b[0];
    }
    __syncthreads();
    if (tid == 0) {
        float mx = sw[0];
        for (int s = 1; s < 10; s++) mx = fmaxf(mx, sw[s]);
        float sum = 0.f;
        for (int s = 0; s < 10; s++) { sw[s] = expf(sw[s] - mx); sum += sw[s]; }
        for (int s = 0; s < 10; s++) sw[s] /= sum;
    }
    __syncthreads();
    for (int d = tid; d < 512; d += 256) {
        float a = 0.f;
#pragma unroll
        for (int s = 0; s < 10; s++) a += sw[s] * documents[(size_t)(b * 10 + s) * 512 + d];
        dr[d] = a;
    }
    __syncthreads();
    {
        float a = bb1[tid], a2 = tb1[tid];
        const float* w1 = bW1 + (size_t)tid * 512;
        const float* w2 = tW1 + (size_t)tid * 512;
        for (int k = 0; k < 512; k++) { float x = dr[k]; a += x * w1[k]; a2 += x * w2[k]; }
        h1s[tid] = tanhf(a); t1s[tid] = tanhf(a2);
    }
    __syncthreads();
    if (tid < 5) {
        float a = bb2[tid];
        const float* wp = bW2 + (size_t)tid * 256;
        for (int k = 0; k < 256; k++) a += h1s[k] * wp[k];
        lg[tid] = tanhf(a);
    }
    if (tid == 32) {
        float a = tb2[0];
        for (int k = 0; k < 256; k++) a += t1s[k] * tW2[k];
        out[320 + b] = 1.f / (1.f + expf(-tanhf(a)));
    }
    __syncthreads();
    if (tid == 0) {
        float mx = lg[0];
        for (int j = 1; j < 5; j++) mx = fmaxf(mx, lg[j]);
        float sum = 0.f, e[5];
        for (int j = 0; j < 5; j++) { e[j] = expf(lg[j] - mx); sum += e[j]; }
        for (int j = 0; j < 5; j++) out[b * 5 + j] = e[j] / sum;
    }
}

extern "C" void kernel_launch(void* const* d_in, const int* in_sizes, int n_in,
                              void* d_out, int out_size, void* d_ws, size_t ws_size,
                              hipStream_t stream)
{
    (void)in_sizes; (void)n_in; (void)out_size; (void)ws_size;
    const int*   input_ids = (const int*)d_in[0];
    const int*   urls      = (const int*)d_in[1];
    const int*   titles    = (const int*)d_in[2];
    const float* emb       = (const float*)d_in[3];
    const float* sen_wih_f = (const float*)d_in[4];
    const float* sen_whh_f = (const float*)d_in[5];
    const float* sen_b_f   = (const float*)d_in[6];
    const float* sen_wih_b = (const float*)d_in[7];
    const float* sen_whh_b = (const float*)d_in[8];
    const float* sen_b_b   = (const float*)d_in[9];
    const float* trans     = (const float*)d_in[10];
    const float* sb_bias   = (const float*)d_in[11];
    const float* doc_wih_f = (const float*)d_in[12];
    const float* doc_whh_f = (const float*)d_in[13];
    const float* doc_b_f   = (const float*)d_in[14];
    const float* doc_wih_b = (const float*)d_in[15];
    const float* doc_whh_b = (const float*)d_in[16];
    const float* doc_b_b   = (const float*)d_in[17];
    const float* attn_W    = (const float*)d_in[18];
    const float* attn_b    = (const float*)d_in[19];
    const float* bias_W1   = (const float*)d_in[20];
    const float* bias_b1   = (const float*)d_in[21];
    const float* bias_W2   = (const float*)d_in[22];
    const float* bias_b2   = (const float*)d_in[23];
    const float* truth_W1  = (const float*)d_in[24];
    const float* truth_b1  = (const float*)d_in[25];
    const float* truth_W2  = (const float*)d_in[26];
    const float* truth_b2  = (const float*)d_in[27];
    float* out = (float*)d_out;

    // ------------------------------------------------------------------
    // Workspace layout with lifetime overlays (offsets in FLOATS).
    // Slot A = xw_all [0 .. 41,287,680): live D2–D3. After D3 overlaid by
    //   biasedBf(+0), xw_doc(+163,840), documents(+1,474,560), vbuf(+1,802,240).
    // Slot B = Abf [41,287,680 .. +3,225,600): live D1–D2. After D2 overlaid by
    //   sentences(+0), headings(+327,680), WhhSbf(+360,448), WhhDbf(+622,592),
    //   hbA(+884,736), hbB(+1,064,960), hdA(+1,245,184), hdB(+1,261,568),
    //   bars(+1,277,952).
    // Slot C = Wsen [44,513,280 .. +327,680). Slot D = Wdoc [44,840,960 .. +524,288).
    // ------------------------------------------------------------------
    float* ws = (float*)d_ws;
    float* xw_all      = ws;
    float* xw_head     = xw_all + (size_t)19200 * 2048;
    unsigned* biasedBf = (unsigned*)(ws + 0);
    float* xw_doc      = ws + 163840;
    float* documents   = ws + 1474560;
    float* vbuf        = ws + 1802240;

    float* slotB       = ws + 41287680;
    unsigned* Abf      = (unsigned*)slotB;
    float* sentences   = slotB;
    float* headings    = slotB + 327680;
    unsigned* WhhSbf   = (unsigned*)(slotB + 360448);   // [2][1024][128] u32
    unsigned* WhhDbf   = (unsigned*)(slotB + 622592);
    unsigned short* hbA = (unsigned short*)(slotB + 884736);
    unsigned short* hbB = (unsigned short*)(slotB + 1064960);
    unsigned short* hdA = (unsigned short*)(slotB + 1245184);
    unsigned short* hdB = (unsigned short*)(slotB + 1261568);
    unsigned* barsS    = (unsigned*)(slotB + 1277952);  // 88 pair counters, 16-uint stride
    unsigned* barsD    = barsS + 88 * 16;               // 8 pair counters

    unsigned* Wsen     = (unsigned*)(ws + 44513280);
    unsigned* Wdoc     = (unsigned*)(ws + 44840960);

    dim3 blk(256);

    // D1: gather + bf16 casts
    prep_cast<<<dim3((N0 + N1 + N2 + 255) / 256), blk, 0, stream>>>(
        input_ids, titles, emb, sen_wih_f, sen_wih_b, doc_wih_f, doc_wih_b,
        Abf, Wsen, Wdoc);

    // D2: sentence+title input projection
    proj_mfma<<<dim3(158, 16), blk, 0, stream>>>(
        (const unsigned short*)Abf, 20160, 320,
        (const unsigned short*)Wsen, sen_b_f, sen_b_b, xw_all);

    // bars zero + Whh bf16 cast (slot B dead after D2)
    hipMemsetAsync(barsS, 0, (88 + 8) * 16 * sizeof(unsigned), stream);
    prep_whh<<<dim3(2048), blk, 0, stream>>>(
        sen_whh_f, sen_whh_b, doc_whh_f, doc_whh_b, WhhSbf, WhhDbf);

    // D3: persistent sentence/heading BiLSTM (88 pairs x 2 blocks x 512 thr)
    lstm_sen2<<<dim3(176), dim3(512), 0, stream>>>(
        xw_all, xw_head, (const unsigned short*)WhhSbf, hbA, hbB,
        sentences, headings, barsS);

    // D4: SourceBias
    source_bias<<<dim3(640), blk, 0, stream>>>(sentences, urls, trans, sb_bias, biasedBf);

    // D5: document input projection
    proj_mfma<<<dim3(5, 16), blk, 0, stream>>>(
        (const unsigned short*)biasedBf, 640, 512,
        (const unsigned short*)Wdoc, doc_b_f, doc_b_b, xw_doc);

    // D6: persistent document BiLSTM (8 pairs x 2 blocks x 512 thr)
    lstm_doc2<<<dim3(16), dim3(512), 0, stream>>>(
        xw_doc, (const unsigned short*)WhhDbf, hdA, hdB, documents, barsD);

    // D7/D8: attention + heads
    attn_v<<<dim3(64), blk, 0, stream>>>(attn_W, headings, vbuf);
    attn_heads<<<dim3(64), blk, 0, stream>>>(documents, vbuf, attn_b,
                                             bias_W1, bias_b1, bias_W2, bias_b2,
                                             truth_W1, truth_b1, truth_W2, truth_b2,
                                             out);
}